// Round 5
// baseline (11587.609 us; speedup 1.0000x reference)
//
#include <hip/hip_runtime.h>
#include <math.h>

// ---------------- problem constants ----------------
#define TS   2048   // timesteps
#define NN   100    // nodes
#define FD   128    // input features
#define HD   512    // hidden
#define G3   1536   // 3*HD
#define NG   7      // node groups of 16
#define NPAD 112    // padded node rows (NG*16): h buffers MUST cover these
#define NSL  8      // hidden slices (64 h-cols each)
#define KNN  8
#define GIN  704    // HD + 64 + 128
#define GH   256
#define GOUT 128

typedef float    f32x4  __attribute__((ext_vector_type(4)));
typedef unsigned u32x4  __attribute__((ext_vector_type(4)));
typedef __bf16   bf16x8 __attribute__((ext_vector_type(8)));
#define MFMA16(a, b, c) __builtin_amdgcn_mfma_f32_16x16x32_bf16((a), (b), (c), 0, 0, 0)

#define WXST 136   // Wx/Ax LDS row stride (bf16): 272B, 16B-aligned

__device__ __forceinline__ float sig_(float v) {
    return __builtin_amdgcn_rcpf(1.f + __expf(-v));
}
__device__ __forceinline__ float tanh_(float v) {
    float e = __expf(2.f * v);
    return 1.f - 2.f * __builtin_amdgcn_rcpf(e + 1.f);   // saturates at +/-1
}

// =====================================================================
// Self-validating h exchange (agent scope, sc0 sc1 -> coherent at LLC).
// Each h element is published as one u32: (step+1)<<16 | bf16(h).
// 32-bit stores are atomic -> value+epoch always travel together; the
// consumer validates the high half of every loaded word against t and
// retries while stale. No separate tag store, no producer-side ack, no
// tag-poll round trip: the exchange is ONE load round trip once the
// stores are visible.
// Safety: a block can lead its slowest peer by <2 steps (it needs all
// peers' h_t before producing h_{t+2} into the same parity buffer), so
// a tag-t word is immutable while any peer is still consuming step t ->
// exact-match check, chunk-wise consume is sound.
// SIZING: blocks address padded rows [0,NPAD) with no NN guard -> both
// h buffers are [NPAD][HD] u32. (Round-4 hang: 100-row buffers let
// group 6 spill into the peer buffer, corrupting tags -> infinite retry.)
// =====================================================================

// 4 frags (k-cols [128c,128c+128)): 8 dwordx4 at voff = hv_voff + 512c
__device__ __forceinline__ void loadw8(const unsigned* base, unsigned voff, u32x4* h) {
    asm volatile(
        "global_load_dwordx4 %0, %8, %9 sc0 sc1\n\t"
        "global_load_dwordx4 %1, %8, %9 offset:16 sc0 sc1\n\t"
        "global_load_dwordx4 %2, %8, %9 offset:128 sc0 sc1\n\t"
        "global_load_dwordx4 %3, %8, %9 offset:144 sc0 sc1\n\t"
        "global_load_dwordx4 %4, %8, %9 offset:256 sc0 sc1\n\t"
        "global_load_dwordx4 %5, %8, %9 offset:272 sc0 sc1\n\t"
        "global_load_dwordx4 %6, %8, %9 offset:384 sc0 sc1\n\t"
        "global_load_dwordx4 %7, %8, %9 offset:400 sc0 sc1\n\t"
        "s_waitcnt vmcnt(0)"
        : "=&v"(h[0]), "=&v"(h[1]), "=&v"(h[2]), "=&v"(h[3]),
          "=&v"(h[4]), "=&v"(h[5]), "=&v"(h[6]), "=&v"(h[7])
        : "v"(voff), "s"(base) : "memory");
}

// 4 tagged words, rows e=0..3 (row stride 2048B); fire-and-forget
__device__ __forceinline__ void storew4(unsigned* base, unsigned voff,
                                        unsigned v0, unsigned v1, unsigned v2, unsigned v3) {
    unsigned voff2 = voff + 4096u;
    asm volatile(
        "global_store_dword %4, %0, %6 sc0 sc1\n\t"
        "global_store_dword %4, %1, %6 offset:2048 sc0 sc1\n\t"
        "global_store_dword %5, %2, %6 sc0 sc1\n\t"
        "global_store_dword %5, %3, %6 offset:2048 sc0 sc1"
        :: "v"(v0), "v"(v1), "v"(v2), "v"(v3), "v"(voff), "v"(voff2), "s"(base) : "memory");
}

__device__ __forceinline__ bool valid8(const u32x4* hw, unsigned tt) {
    unsigned ok = 1u;
    #pragma unroll
    for (int q = 0; q < 8; ++q) {
        ok &= (unsigned)((hw[q][0] >> 16) == tt);
        ok &= (unsigned)((hw[q][1] >> 16) == tt);
        ok &= (unsigned)((hw[q][2] >> 16) == tt);
        ok &= (unsigned)((hw[q][3] >> 16) == tt);
    }
    return __all((int)ok);
}

__device__ __forceinline__ bf16x8 pack8(u32x4 a, u32x4 b) {
    u32x4 r;
    r[0] = (a[0] & 0xffffu) | (a[1] << 16);
    r[1] = (a[2] & 0xffffu) | (a[3] << 16);
    r[2] = (b[0] & 0xffffu) | (b[1] << 16);
    r[3] = (b[2] & 0xffffu) | (b[3] << 16);
    return __builtin_bit_cast(bf16x8, r);
}

__device__ __forceinline__ bf16x8 cvt8(const float* p) {
    float4 a = *(const float4*)p, b = *(const float4*)(p + 4);
    bf16x8 r;
    r[0] = (__bf16)a.x; r[1] = (__bf16)a.y; r[2] = (__bf16)a.z; r[3] = (__bf16)a.w;
    r[4] = (__bf16)b.x; r[5] = (__bf16)b.y; r[6] = (__bf16)b.z; r[7] = (__bf16)b.w;
    return r;
}

// =====================================================================
// Persistent GRU main loop. 56 blocks x 256 threads (4 waves).
// block (g,s): nodes [16g,16g+16), h-cols [64s,64s+64); wave w: 16 cols.
// Whh B-frags (48 = 192 regs) in registers; Wih in LDS; hold in regs.
// Cross-block h exchange: self-validating tagged u32 words, consumed in
// 4 chunks (32 VGPRs each) so first-chunk retry absorbs straggler
// latency while later chunks pass first try.
// =====================================================================
__device__ void gru_loop(const float* __restrict__ x,
                         const float* __restrict__ Wih, const float* __restrict__ Whh,
                         const float* __restrict__ bih, const float* __restrict__ bhh,
                         unsigned* h0buf, unsigned* h1buf, float* enc,
                         int g, int s, __bf16* WxP, __bf16* AxP)
{
    const int tid = threadIdx.x;
    const int w   = tid >> 6;
    const int ln  = tid & 63;
    const int nb  = g * 16;
    const int mi  = ln & 15;
    const int kq8 = (ln >> 4) * 8;
    const int cl  = 16 * w + mi;
    const int ch  = 64 * s + cl;

    // ---- one-time: Wih slice -> LDS (192 gate rows x 128 K) ----
    for (int idx = tid; idx < 192 * 32; idx += 256) {
        int row = idx >> 5, c4 = idx & 31;
        int grow = (row >> 6) * HD + 64 * s + (row & 63);
        float4 v = ((const float4*)(Wih + (size_t)grow * FD))[c4];
        __bf16* d = WxP + row * WXST + c4 * 4;
        d[0] = (__bf16)v.x; d[1] = (__bf16)v.y; d[2] = (__bf16)v.z; d[3] = (__bf16)v.w;
    }

    // ---- one-time: Whh B-frags -> registers ----
    bf16x8 wR[16], wZ[16], wN[16];
    {
        const float* pR = Whh + (size_t)ch * HD;
        const float* pZ = Whh + (size_t)(HD + ch) * HD;
        const float* pN = Whh + (size_t)(2 * HD + ch) * HD;
        #pragma unroll
        for (int kk = 0; kk < 16; ++kk) {
            int ko = 32 * kk + kq8;
            wR[kk] = cvt8(pR + ko);
            wZ[kk] = cvt8(pZ + ko);
            wN[kk] = cvt8(pN + ko);
        }
    }
    const float bR  = bih[ch] + bhh[ch];
    const float bZ  = bih[HD + ch] + bhh[HD + ch];
    const float bNX = bih[2 * HD + ch];
    const float bNH = bhh[2 * HD + ch];

    const int xrow  = tid >> 4;
    const int xnode = nb + xrow;
    const int xcol  = (tid & 15) * 8;

    // ---- prologue: stage x_0, x-part MFMAs for t=0 ----
    {
        float4 xa = {0.f, 0.f, 0.f, 0.f}, xb = xa;
        if (xnode < NN) {
            const float* xp = x + (size_t)xnode * FD + xcol;
            xa = ((const float4*)xp)[0];
            xb = ((const float4*)xp)[1];
        }
        bf16x8 v;
        v[0] = (__bf16)xa.x; v[1] = (__bf16)xa.y; v[2] = (__bf16)xa.z; v[3] = (__bf16)xa.w;
        v[4] = (__bf16)xb.x; v[5] = (__bf16)xb.y; v[6] = (__bf16)xb.z; v[7] = (__bf16)xb.w;
        *(bf16x8*)(AxP + (size_t)xrow * WXST + xcol) = v;
    }
    __syncthreads();

    f32x4 accR = {0.f, 0.f, 0.f, 0.f}, accZ = accR, accNX = accR, accNH = accR;
    #pragma unroll
    for (int kk = 0; kk < 4; ++kk) {
        int ko = 32 * kk + kq8;
        bf16x8 av = *(const bf16x8*)(AxP + (size_t)mi * WXST + ko);
        accR  = MFMA16(av, *(const bf16x8*)(WxP + (size_t)cl * WXST + ko),         accR);
        accZ  = MFMA16(av, *(const bf16x8*)(WxP + (size_t)(64 + cl) * WXST + ko),  accZ);
        accNX = MFMA16(av, *(const bf16x8*)(WxP + (size_t)(128 + cl) * WXST + ko), accNX);
    }

    float hold[4] = {0.f, 0.f, 0.f, 0.f};

    const unsigned hv_voff = ((unsigned)(nb + mi) * HD + (unsigned)kq8) * 4u;
    const unsigned st_voff = ((unsigned)(nb + (ln >> 4) * 4) * HD + (unsigned)ch) * 4u;

    #pragma unroll 1
    for (int t = 0; t < TS; ++t) {
        unsigned* hcur = (t & 1) ? h1buf : h0buf;
        unsigned* hnxt = (t & 1) ? h0buf : h1buf;
        const unsigned tt = (unsigned)t;

        // ---- prefetch x_{t+1} (plain cached loads; overlaps poll) ----
        float4 xa = {0.f, 0.f, 0.f, 0.f}, xb = xa;
        if (t + 1 < TS && xnode < NN) {
            const float* xp = x + ((size_t)(t + 1) * NN + xnode) * FD + xcol;
            xa = ((const float4*)xp)[0];
            xb = ((const float4*)xp)[1];
        }

        // ---- h_t: 4 chunks of load+validate+consume ----
        #pragma unroll
        for (int c = 0; c < 4; ++c) {
            u32x4 hw[8];
            unsigned vo = hv_voff + 512u * (unsigned)c;
            do { loadw8(hcur, vo, hw); } while (!valid8(hw, tt));
            #pragma unroll
            for (int kk = 0; kk < 4; ++kk) {
                bf16x8 av = pack8(hw[2 * kk], hw[2 * kk + 1]);
                accR  = MFMA16(av, wR[4 * c + kk], accR);
                accZ  = MFMA16(av, wZ[4 * c + kk], accZ);
                accNH = MFMA16(av, wN[4 * c + kk], accNH);
            }
        }

        // ---- gates + h update (hold in regs) + tagged publish ----
        const unsigned tagn = (unsigned)(t + 1) << 16;
        unsigned pw[4];
        #pragma unroll
        for (int e = 0; e < 4; ++e) {
            float rv = sig_(accR[e] + bR);
            float zv = sig_(accZ[e] + bZ);
            float nv = tanh_(accNX[e] + bNX + rv * (accNH[e] + bNH));
            float hnew = (1.f - zv) * nv + zv * hold[e];
            hold[e] = hnew;
            pw[e] = tagn | (unsigned)__builtin_bit_cast(unsigned short, (__bf16)hnew);
        }
        storew4(hnxt, st_voff, pw[0], pw[1], pw[2], pw[3]);
        // no ack wait, no barrier, no tag store: words self-validate

        // ---- slack window: stage x_{t+1}, run its x-part MFMAs ----
        const int nslot = (t + 1) & 1;
        if (t + 1 < TS) {
            bf16x8 v;
            v[0] = (__bf16)xa.x; v[1] = (__bf16)xa.y; v[2] = (__bf16)xa.z; v[3] = (__bf16)xa.w;
            v[4] = (__bf16)xb.x; v[5] = (__bf16)xb.y; v[6] = (__bf16)xb.z; v[7] = (__bf16)xb.w;
            *(bf16x8*)(AxP + ((size_t)nslot * 16 + xrow) * WXST + xcol) = v;
        }
        __syncthreads();   // Ax slot write -> read separation (1 barrier/step)

        accR = {0.f, 0.f, 0.f, 0.f}; accZ = accR; accNX = accR; accNH = accR;
        if (t + 1 < TS) {
            #pragma unroll
            for (int kk = 0; kk < 4; ++kk) {
                int ko = 32 * kk + kq8;
                bf16x8 av = *(const bf16x8*)(AxP + ((size_t)nslot * 16 + mi) * WXST + ko);
                accR  = MFMA16(av, *(const bf16x8*)(WxP + (size_t)cl * WXST + ko),         accR);
                accZ  = MFMA16(av, *(const bf16x8*)(WxP + (size_t)(64 + cl) * WXST + ko),  accZ);
                accNX = MFMA16(av, *(const bf16x8*)(WxP + (size_t)(128 + cl) * WXST + ko), accNX);
            }
        }
    }

    // ---- epilogue: final h -> enc (fp32) ----
    #pragma unroll
    for (int e = 0; e < 4; ++e) {
        int row = (ln >> 4) * 4 + e;
        if (nb + row < NN)
            enc[(size_t)(nb + row) * HD + ch] = hold[e];
    }
}

__global__ __launch_bounds__(256, 1) void gru_kernel(
    const float* __restrict__ x, const float* __restrict__ Wih,
    const float* __restrict__ Whh, const float* __restrict__ bih,
    const float* __restrict__ bhh,
    unsigned* h0buf, unsigned* h1buf, float* enc)
{
    __shared__ __align__(16) __bf16 Wx[192 * WXST];
    __shared__ __align__(16) __bf16 Ax[2 * 16 * WXST];

    const int g = blockIdx.x >> 3;       // 0..6
    const int s = blockIdx.x & 7;        // 0..7

    gru_loop(x, Wih, Whh, bih, bhh, h0buf, h1buf, enc, g, s, Wx, Ax);
}

// ===================== epilogue (tiny) =====================

__global__ void e1_gnn_in(const float* __restrict__ enc, const float* __restrict__ flat,
                          const float* __restrict__ emb, const float* __restrict__ fW,
                          const float* __restrict__ fb, float* __restrict__ gnn)
{
    int i = blockIdx.x, tid = threadIdx.x;
    const float4* src = (const float4*)(enc + (size_t)i * HD);
    float4* dst = (float4*)(gnn + (size_t)i * GIN);
    dst[tid] = src[tid];
    if (tid < 64) {
        float acc = fb[tid];
        const float* w  = fW + tid * 32;
        const float* fl = flat + i * 32;
        #pragma unroll
        for (int k = 0; k < 32; ++k) acc = fmaf(fl[k], w[k], acc);
        gnn[(size_t)i * GIN + HD + tid] = acc;
    }
    gnn[(size_t)i * GIN + HD + 64 + tid] = emb[(size_t)i * FD + tid];
}

__global__ void e2a_norm(const float* __restrict__ emb, float* __restrict__ mx)
{
    int j = threadIdx.x;
    if (j < NN) {
        float acc = 0.f;
        const float* e = emb + (size_t)j * FD;
        for (int d = 0; d < FD; ++d) acc = fmaf(e[d], e[d], acc);
        mx[j] = fmaxf(sqrtf(acc), 1e-8f);
    }
}

__global__ void e2b_knn(const float* __restrict__ emb, const float* __restrict__ mx,
                        int* __restrict__ tgt)
{
    int i = blockIdx.x, tid = threadIdx.x;   // 128 threads
    __shared__ float ei[FD];
    __shared__ float srow[NN];
    ei[tid] = emb[(size_t)i * FD + tid];
    __syncthreads();
    if (tid < NN) {
        float acc = 0.f;
        const float* e = emb + (size_t)tid * FD;
        for (int d = 0; d < FD; ++d) acc = fmaf(ei[d], e[d], acc);
        float sim = acc / (mx[i] * mx[tid]);
        srow[tid] = (tid == i) ? 0.f : sim;
    }
    __syncthreads();
    if (tid == 0) {
        for (int t = 0; t < KNN; ++t) {
            float best = -1e30f; int bi = 0;
            for (int j = 0; j < NN; ++j) { float v = srow[j]; if (v > best) { best = v; bi = j; } }
            srow[bi] = -1e30f;
            tgt[i * KNN + t] = bi;
        }
    }
}

__global__ void e3_agg(const float* __restrict__ xin, const int* __restrict__ tgt,
                       float* __restrict__ agg, float* __restrict__ cnt, int D)
{
    int e = blockIdx.x, src = e >> 3, tg = tgt[e];
    for (int d = threadIdx.x; d < D; d += blockDim.x)
        atomicAdd(&agg[(size_t)tg * D + d], xin[(size_t)src * D + d]);
    if (threadIdx.x == 0) atomicAdd(&cnt[tg], 1.0f);
}

__global__ void e4_sage(const float* __restrict__ agg, const float* __restrict__ xin,
                        const float* __restrict__ cnt,
                        const float* __restrict__ Wl, const float* __restrict__ Wr,
                        const float* __restrict__ b, float* __restrict__ out,
                        int Din, int Dout, int dorelu)
{
    int j = blockIdx.x, o = threadIdx.x;
    extern __shared__ float sm[];
    float* la = sm;
    float* lx = sm + Din;
    for (int d = o; d < Din; d += blockDim.x) {
        la[d] = agg[(size_t)j * Din + d];
        lx[d] = xin[(size_t)j * Din + d];
    }
    __syncthreads();
    float inv = 1.f / fmaxf(cnt[j], 1.f);
    float acc1 = 0.f, acc2 = 0.f;
    const float* wl = Wl + (size_t)o * Din;
    const float* wr = Wr + (size_t)o * Din;
    for (int k = 0; k < Din; ++k) {
        acc1 = fmaf(la[k], wl[k], acc1);
        acc2 = fmaf(lx[k], wr[k], acc2);
    }
    float v = fmaf(acc1, inv, acc2) + b[o];
    if (dorelu) v = fmaxf(v, 0.f);
    out[(size_t)j * Dout + o] = v;
}

__global__ void e7_out(const float* __restrict__ g, const float* __restrict__ enc,
                       const float* __restrict__ oW, const float* __restrict__ ob,
                       float* __restrict__ out)
{
    int j = threadIdx.x;
    if (j < NN) {
        float acc = ob[0];
        const float* gr = g + (size_t)j * GOUT;
        for (int d = 0; d < GOUT; ++d) acc = fmaf(gr[d], oW[d], acc);
        const float* er = enc + (size_t)j * HD;
        for (int d = 0; d < HD; ++d) acc = fmaf(er[d], oW[GOUT + d], acc);
        out[j] = 1.f / (1.f + expf(-acc));
    }
}

// ===================== launch =====================
extern "C" void kernel_launch(void* const* d_in, const int* in_sizes, int n_in,
                              void* d_out, int out_size, void* d_ws, size_t ws_size,
                              hipStream_t stream)
{
    const float* x    = (const float*)d_in[0];
    const float* flat = (const float*)d_in[1];
    const float* emb  = (const float*)d_in[2];
    const float* Wih  = (const float*)d_in[3];
    const float* Whh  = (const float*)d_in[4];
    const float* bih  = (const float*)d_in[5];
    const float* bhh  = (const float*)d_in[6];
    const float* fW   = (const float*)d_in[7];
    const float* fb   = (const float*)d_in[8];
    const float* s1Wl = (const float*)d_in[9];
    const float* s1Wr = (const float*)d_in[10];
    const float* s1b  = (const float*)d_in[11];
    const float* s2Wl = (const float*)d_in[12];
    const float* s2Wr = (const float*)d_in[13];
    const float* s2b  = (const float*)d_in[14];
    const float* oW   = (const float*)d_in[15];
    const float* ob   = (const float*)d_in[16];
    float* out = (float*)d_out;

    // workspace layout (bytes). Zero zone first -> single memset.
    // h buffers: u32 [NPAD=112][HD] tagged words (tag 0 == valid zeros @ t=0).
    char* p = (char*)d_ws;
    unsigned* h0buf = (unsigned*)(p + 0);        // 229376  [zero]
    unsigned* h1buf = (unsigned*)(p + 229376);   // 229376  [zero]
    float*    agg1  = (float*)(p + 458752);      // 281600  [zero]
    float*    agg2  = (float*)(p + 740352);      // 102400  [zero]
    float*    cnt1  = (float*)(p + 842752);      // 448     [zero]
    float*    cnt2  = (float*)(p + 843200);      // 448     [zero]
    float*    enc   = (float*)(p + 843648);      // 229376
    float*    gnn   = (float*)(p + 1073024);     // 281600
    float*    h1s   = (float*)(p + 1354624);     // 102400
    float*    gbuf  = (float*)(p + 1457024);     // 51200
    float*    mx    = (float*)(p + 1508224);     // 448
    int*      tgt   = (int*)  (p + 1508672);     // 3200
    // total ~1.44 MiB

    (void)hipMemsetAsync(d_ws, 0, 843648, stream);

    gru_kernel<<<NG * NSL, 256, 0, stream>>>(x, Wih, Whh, bih, bhh, h0buf, h1buf, enc);
    e1_gnn_in<<<NN, 128, 0, stream>>>(enc, flat, emb, fW, fb, gnn);
    e2a_norm<<<1, 128, 0, stream>>>(emb, mx);
    e2b_knn<<<NN, 128, 0, stream>>>(emb, mx, tgt);
    e3_agg<<<NN * KNN, 256, 0, stream>>>(gnn, tgt, agg1, cnt1, GIN);
    e4_sage<<<NN, GH, 2 * GIN * sizeof(float), stream>>>(agg1, gnn, cnt1, s1Wl, s1Wr, s1b, h1s, GIN, GH, 1);
    e3_agg<<<NN * KNN, 256, 0, stream>>>(h1s, tgt, agg2, cnt2, GH);
    e4_sage<<<NN, GOUT, 2 * GH * sizeof(float), stream>>>(agg2, h1s, cnt2, s2Wl, s2Wr, s2b, gbuf, GH, GOUT, 0);
    e7_out<<<1, 128, 0, stream>>>(gbuf, enc, oW, ob, out);
}